// Round 14
// baseline (347.703 us; speedup 1.0000x reference)
//
#include <hip/hip_runtime.h>
#include <hip/hip_bf16.h>

#define Bn 2
#define Tn 4096
#define Cn 768
#define Hn 12
#define Dn 64
#define Mn (Bn * Tn)   // 8192
#define PAD 72         // padded LDS row stride (bf16 elems) for attn/transpose
#define QSC 0.18033688011112f   // D^-0.5 * log2(e), folded into Q at gen time

typedef __attribute__((ext_vector_type(8))) short bf16x8;
typedef __attribute__((ext_vector_type(4))) short bf16x4;
typedef __attribute__((ext_vector_type(4))) float f32x4;

typedef const __attribute__((address_space(1))) unsigned int* gas_ptr;
typedef __attribute__((address_space(3))) unsigned int* las_ptr;

__device__ __forceinline__ float b2f(unsigned short u) {
    return __uint_as_float(((unsigned int)u) << 16);
}
__device__ __forceinline__ unsigned short f2b(float f) {
    unsigned int x = __float_as_uint(f);
    x += 0x7FFFu + ((x >> 16) & 1u);   // round-to-nearest-even
    return (unsigned short)(x >> 16);
}
// packed f32x2 -> bf16x2 (single VALU op)
__device__ __forceinline__ unsigned int cvt_pk_bf16(float lo, float hi) {
    unsigned int r;
    asm("v_cvt_pk_bf16_f32 %0, %1, %2" : "=v"(r) : "v"(lo), "v"(hi));
    return r;
}

// Async global->LDS, 16B/lane. LDS dest = wave-uniform base + lane*16.
__device__ __forceinline__ void async_ld16(const unsigned short* g, unsigned short* l) {
    __builtin_amdgcn_global_load_lds((gas_ptr)(const void*)g, (las_ptr)(void*)l, 16, 0, 0);
}

// ---------------------------------------------------------------------------
// prep1: fused {dtype-detect + transpose wqkv + convert x + (opt) transpose
// wproj}. Blocks [0,432): wqkv transpose tiles; [432,3504): x convert;
// [3504,3648): wproj transpose tiles (only when launched with 3648 blocks).
// ---------------------------------------------------------------------------
__global__ __launch_bounds__(256) void prep1_k(
    const void* __restrict__ wqkv, unsigned short* __restrict__ wqkvT,
    const void* __restrict__ x, unsigned short* __restrict__ xb,
    const void* __restrict__ wproj, unsigned short* __restrict__ wprojT,
    int* __restrict__ flag)
{
    __shared__ unsigned short Ts[64][PAD];
    __shared__ int anyf;
    const int tid = threadIdx.x;
    if (tid == 0) anyf = 0;
    __syncthreads();
    {   // per-block detect: 2048 bf16-view samples of wqkv
        int4 v = reinterpret_cast<const int4*>(wqkv)[tid];
        const unsigned short* u = reinterpret_cast<const unsigned short*>(&v);
        int bad = 0;
#pragma unroll
        for (int j = 0; j < 8; ++j) {
            const unsigned int e = (u[j] >> 7) & 0xFFu;
            bad |= (e >= 0x88u) ? 1 : 0;
        }
        if (bad) atomicOr(&anyf, 1);
    }
    __syncthreads();
    const bool f32 = (anyf != 0);
    if (tid == 0 && blockIdx.x == 0) *flag = anyf;

    if (blockIdx.x >= 432 && blockIdx.x < 3504) {
        // convert x -> bf16 flat copy, 8 elems/thread
        const size_t i = ((size_t)(blockIdx.x - 432) * 256 + tid) * 8;
        union { int4 v; unsigned short u[8]; } pk;
        if (f32) {
            const float* p = (const float*)x + i;
            float4 a = *reinterpret_cast<const float4*>(p);
            float4 b = *reinterpret_cast<const float4*>(p + 4);
            float t[8] = {a.x, a.y, a.z, a.w, b.x, b.y, b.z, b.w};
#pragma unroll
            for (int j = 0; j < 8; ++j) pk.u[j] = f2b(t[j]);
        } else {
            pk.v = *reinterpret_cast<const int4*>((const unsigned short*)x + i);
        }
        *reinterpret_cast<int4*>(xb + i) = pk.v;
        return;
    }

    // transpose path: wqkv (blocks < 432) or wproj (blocks >= 3504)
    const bool isW2 = (blockIdx.x >= 3504);
    const void* in = isW2 ? wproj : wqkv;
    unsigned short* out = isW2 ? wprojT : wqkvT;
    const int K = Cn;
    const int N = isW2 ? Cn : 3 * Cn;
    const int id = isW2 ? ((int)blockIdx.x - 3504) : (int)blockIdx.x;
    const int ncols = N / 64;
    const int nB = (id % ncols) * 64, kB = (id / ncols) * 64;
#pragma unroll
    for (int it = 0; it < 2; ++it) {
        const int r = (tid >> 3) + it * 32;   // k-row in tile
        const int c = (tid & 7) * 8;          // n-col chunk
        float t[8];
        if (f32) {
            const float* p = (const float*)in + (size_t)(kB + r) * N + nB + c;
            float4 a = *reinterpret_cast<const float4*>(p);
            float4 b = *reinterpret_cast<const float4*>(p + 4);
            t[0]=a.x;t[1]=a.y;t[2]=a.z;t[3]=a.w;t[4]=b.x;t[5]=b.y;t[6]=b.z;t[7]=b.w;
        } else {
            int4 v = *reinterpret_cast<const int4*>((const unsigned short*)in + (size_t)(kB + r) * N + nB + c);
            const unsigned short* u = reinterpret_cast<const unsigned short*>(&v);
#pragma unroll
            for (int j = 0; j < 8; ++j) t[j] = b2f(u[j]);
        }
#pragma unroll
        for (int j = 0; j < 8; ++j) Ts[c + j][r] = f2b(t[j]);
    }
    __syncthreads();
#pragma unroll
    for (int it = 0; it < 2; ++it) {
        const int n = (tid >> 3) + it * 32;
        const int k = (tid & 7) * 8;
        *reinterpret_cast<int4*>(out + (size_t)(nB + n) * K + kB + k) =
            *reinterpret_cast<const int4*>(&Ts[n][k]);
    }
}

// Transpose weight: in[K][N] (fp32 or bf16 per flag) -> out[N][K] bf16. 64x64 tiles.
// (fallback path only)
__global__ __launch_bounds__(256) void transpose_w_k(
    const void* __restrict__ in, unsigned short* __restrict__ out,
    int K, int N, const int* __restrict__ flag)
{
    __shared__ unsigned short Ts[64][PAD];   // [n][k]
    const int tid = threadIdx.x;
    const int kB = blockIdx.y * 64, nB = blockIdx.x * 64;
    const bool f32 = (*flag != 0);
#pragma unroll
    for (int it = 0; it < 2; ++it) {
        const int r = (tid >> 3) + it * 32;   // k-row in tile
        const int c = (tid & 7) * 8;          // n-col chunk
        float t[8];
        if (f32) {
            const float* p = (const float*)in + (size_t)(kB + r) * N + nB + c;
            float4 a = *reinterpret_cast<const float4*>(p);
            float4 b = *reinterpret_cast<const float4*>(p + 4);
            t[0]=a.x;t[1]=a.y;t[2]=a.z;t[3]=a.w;t[4]=b.x;t[5]=b.y;t[6]=b.z;t[7]=b.w;
        } else {
            int4 v = *reinterpret_cast<const int4*>((const unsigned short*)in + (size_t)(kB + r) * N + nB + c);
            const unsigned short* u = reinterpret_cast<const unsigned short*>(&v);
#pragma unroll
            for (int j = 0; j < 8; ++j) t[j] = b2f(u[j]);
        }
#pragma unroll
        for (int j = 0; j < 8; ++j) Ts[c + j][r] = f2b(t[j]);
    }
    __syncthreads();
#pragma unroll
    for (int it = 0; it < 2; ++it) {
        const int n = (tid >> 3) + it * 32;
        const int k = (tid & 7) * 8;
        *reinterpret_cast<int4*>(out + (size_t)(nB + n) * K + kB + k) =
            *reinterpret_cast<const int4*>(&Ts[n][k]);
    }
}

// ---------------------------------------------------------------------------
// MFMA GEMM v2 (verified round 10/11): 128x128 tile, BK=32, single-barrier
// double-buffered global_load_lds staging, XCD-chunked swizzle.
// EPI==0: row-major store. EPI==1: QKV split, Q pre-scaled by QSC, V
// written transposed [B,H,D,T] (8B packed stores).
// ---------------------------------------------------------------------------
template <int EPI>
__global__ __launch_bounds__(256) void gemm_lds(
    const unsigned short* __restrict__ A, const unsigned short* __restrict__ Bt,
    void* __restrict__ Out, unsigned short* __restrict__ Qo,
    unsigned short* __restrict__ Ko, unsigned short* __restrict__ Vo,
    int M, int N, int K, const int* __restrict__ flag)
{
    __shared__ unsigned short As[2][8 * 512];   // buf x 8 chunks (16 rows x 32 k)
    __shared__ unsigned short Bs[2][8 * 512];
    const int tid = threadIdx.x;
    const int w = tid >> 6, l = tid & 63;
    const int l15 = l & 15, l4 = l >> 4;

    // XCD-chunked swizzle (identity when nwg not divisible by 8)
    const int gx = (int)gridDim.x;
    const int nwg = gx * (int)gridDim.y;
    int fid = (int)blockIdx.y * gx + (int)blockIdx.x;
    if ((nwg & 7) == 0) fid = (fid & 7) * (nwg >> 3) + (fid >> 3);
    const int rowBase = (fid / gx) * 128;
    const int colBase = (fid % gx) * 128;

    const int mq = (w & 1) * 64, nq = (w >> 1) * 64;
    const bool f32 = (*flag != 0);

    f32x4 acc[4][4];
#pragma unroll
    for (int i = 0; i < 4; ++i)
#pragma unroll
        for (int j = 0; j < 4; ++j) acc[i][j] = (f32x4){0.f, 0.f, 0.f, 0.f};

    // stage K-slab 0 -> buf 0: 8 chunks each of A,B; wave w does 2
#pragma unroll
    for (int jj = 0; jj < 2; ++jj) {
        const int c = w * 2 + jj;
        async_ld16(A + (size_t)(rowBase + c * 16 + l15) * K + l4 * 8, &As[0][c * 512]);
        async_ld16(Bt + (size_t)(colBase + c * 16 + l15) * K + l4 * 8, &Bs[0][c * 512]);
    }

    const int nk = K >> 5;
    int cur = 0;
    for (int s = 0; s < nk; ++s) {
        __syncthreads();   // implicit vmcnt(0): buf[cur] landed; joins prior reads of buf[cur^1]

        if (s + 1 < nk) {  // prefetch next slab into buf[cur^1]
            const int kn = (s + 1) << 5;
#pragma unroll
            for (int jj = 0; jj < 2; ++jj) {
                const int c = w * 2 + jj;
                async_ld16(A + (size_t)(rowBase + c * 16 + l15) * K + kn + l4 * 8,
                           &As[cur ^ 1][c * 512]);
                async_ld16(Bt + (size_t)(colBase + c * 16 + l15) * K + kn + l4 * 8,
                           &Bs[cur ^ 1][c * 512]);
            }
        }

        bf16x8 af[4], bf[4];
#pragma unroll
        for (int mt = 0; mt < 4; ++mt)
            af[mt] = *reinterpret_cast<const bf16x8*>(
                &As[cur][((mq >> 4) + mt) * 512 + l * 8]);
#pragma unroll
        for (int nt = 0; nt < 4; ++nt)
            bf[nt] = *reinterpret_cast<const bf16x8*>(
                &Bs[cur][((nq >> 4) + nt) * 512 + l * 8]);
#pragma unroll
        for (int mt = 0; mt < 4; ++mt)
#pragma unroll
            for (int nt = 0; nt < 4; ++nt)
                acc[mt][nt] = __builtin_amdgcn_mfma_f32_16x16x32_bf16(af[mt], bf[nt], acc[mt][nt], 0, 0, 0);
        cur ^= 1;
    }

    // epilogue: C/D layout col=l15, row=l4*4+i
#pragma unroll
    for (int mt = 0; mt < 4; ++mt)
#pragma unroll
        for (int nt = 0; nt < 4; ++nt) {
            const int n0 = colBase + nq + nt * 16 + l15;
            const int m0 = rowBase + mq + mt * 16 + l4 * 4;
            if (EPI == 0) {
#pragma unroll
                for (int i = 0; i < 4; ++i) {
                    if (f32) ((float*)Out)[(size_t)(m0 + i) * N + n0] = acc[mt][nt][i];
                    else ((unsigned short*)Out)[(size_t)(m0 + i) * N + n0] = f2b(acc[mt][nt][i]);
                }
            } else {
                const int sec = n0 / 768;           // uniform over l15 (16-aligned bounds)
                const int cc = n0 - sec * 768;
                const int h = cc >> 6, d = cc & 63;
                const int b = m0 >> 12, t0 = m0 & 4095;   // b uniform over i
                if (sec < 2) {
                    unsigned short* dst = (sec == 0) ? Qo : Ko;
                    const float scl = (sec == 0) ? QSC : 1.0f;   // pre-scale Q
#pragma unroll
                    for (int i = 0; i < 4; ++i)
                        dst[(((size_t)(b * Hn + h) * Tn + t0 + i) * Dn) + d] = f2b(acc[mt][nt][i] * scl);
                } else {
                    // V transposed: vt[b,h,d,t], 4 consecutive t packed into 8B
                    union { unsigned int u[2]; uint2 v; } pk;
                    pk.u[0] = (unsigned int)f2b(acc[mt][nt][0]) |
                              ((unsigned int)f2b(acc[mt][nt][1]) << 16);
                    pk.u[1] = (unsigned int)f2b(acc[mt][nt][2]) |
                              ((unsigned int)f2b(acc[mt][nt][3]) << 16);
                    *reinterpret_cast<uint2*>(
                        &Vo[(((size_t)(b * Hn + h) * Dn + d) * Tn) + t0]) = pk.v;
                }
            }
        }
}

// ---------------------------------------------------------------------------
// Fallback QKV GEMM (verified): VGPR staging with inline fp32->bf16.
// Writes V untransposed; Q pre-scaled by QSC (fallback attn drops its mul).
// ---------------------------------------------------------------------------
__global__ __launch_bounds__(256) void gemm_qkv_fb(
    const void* __restrict__ A, const unsigned short* __restrict__ Bt,
    unsigned short* __restrict__ Qo, unsigned short* __restrict__ Ko,
    unsigned short* __restrict__ Vo, int M, int N, int K,
    const int* __restrict__ flag)
{
    __shared__ unsigned short As[128 * PAD];
    __shared__ unsigned short Bs[128 * PAD];
    const int tid = threadIdx.x;
    const int w = tid >> 6, l = tid & 63;
    const int l15 = l & 15, l4 = l >> 4;
    const int rowBase = blockIdx.y * 128;
    const int colBase = blockIdx.x * 128;
    const int mq = (w & 1) * 64, nq = (w >> 1) * 64;
    const bool af32 = (*flag != 0);

    f32x4 acc[4][4];
#pragma unroll
    for (int i = 0; i < 4; ++i)
#pragma unroll
        for (int j = 0; j < 4; ++j) acc[i][j] = (f32x4){0.f, 0.f, 0.f, 0.f};

    for (int k0 = 0; k0 < K; k0 += 64) {
        __syncthreads();
#pragma unroll
        for (int it = 0; it < 4; ++it) {
            const int s = tid + it * 256;
            const int r = s >> 3, c = (s & 7) * 8;
            union { int4 v; unsigned short u[8]; } pk;
            if (af32) {
                const float* p = (const float*)A + (size_t)(rowBase + r) * K + k0 + c;
                float4 a = *reinterpret_cast<const float4*>(p);
                float4 b = *reinterpret_cast<const float4*>(p + 4);
                float t[8] = {a.x, a.y, a.z, a.w, b.x, b.y, b.z, b.w};
#pragma unroll
                for (int j = 0; j < 8; ++j) pk.u[j] = f2b(t[j]);
            } else {
                pk.v = *reinterpret_cast<const int4*>(
                    (const unsigned short*)A + (size_t)(rowBase + r) * K + k0 + c);
            }
            *reinterpret_cast<int4*>(&As[r * PAD + c]) = pk.v;
            *reinterpret_cast<int4*>(&Bs[r * PAD + c]) =
                *reinterpret_cast<const int4*>(Bt + (size_t)(colBase + r) * K + k0 + c);
        }
        __syncthreads();
#pragma unroll
        for (int kk = 0; kk < 64; kk += 32) {
            bf16x8 af[4], bf[4];
#pragma unroll
            for (int mt = 0; mt < 4; ++mt)
                af[mt] = *reinterpret_cast<const bf16x8*>(&As[(mq + mt * 16 + l15) * PAD + kk + l4 * 8]);
#pragma unroll
            for (int nt = 0; nt < 4; ++nt)
                bf[nt] = *reinterpret_cast<const bf16x8*>(&Bs[(nq + nt * 16 + l15) * PAD + kk + l4 * 8]);
#pragma unroll
            for (int mt = 0; mt < 4; ++mt)
#pragma unroll
                for (int nt = 0; nt < 4; ++nt)
                    acc[mt][nt] = __builtin_amdgcn_mfma_f32_16x16x32_bf16(af[mt], bf[nt], acc[mt][nt], 0, 0, 0);
        }
    }

#pragma unroll
    for (int mt = 0; mt < 4; ++mt)
#pragma unroll
        for (int i = 0; i < 4; ++i) {
            const int m = rowBase + mq + mt * 16 + l4 * 4 + i;
#pragma unroll
            for (int nt = 0; nt < 4; ++nt) {
                const int n0 = colBase + nq + nt * 16 + l15;
                const int sec = n0 / 768;
                const int cc = n0 - sec * 768;
                const int h = cc >> 6, d = cc & 63;
                const int b = m >> 12, t = m & 4095;
                unsigned short* dst = (sec == 0) ? Qo : (sec == 1) ? Ko : Vo;
                const float scl = (sec == 0) ? QSC : 1.0f;
                dst[(((size_t)(b * Hn + h) * Tn + t) * Dn) + d] = f2b(acc[mt][nt][i] * scl);
            }
        }
}

// ---------------------------------------------------------------------------
// MFMA flash attention v7: verified round-13 structure with KVBLK 64->128.
//
// Latency-amortization: the per-stage fixed overhead (barrier join, lgkm
// first-use latency, serial QK->exp->pack->PV chain ramp) is paid per
// barrier; doubling the keys per stage halves barriers per key. NO change
// to wave/lane work assignment or fragment mapping — the verified loops
// are extended: 16 LDS chunks/tile (4/wave), tt 0..7, nst=(q0>>7)+1,
// mask window k0+127>q0. Overhang keys past the causal boundary are
// masked to p=0 (correct for o AND lsum); tail over-reads of K/Vt land in
// adjacent allocated workspace slots. Folded pairs stay balanced:
// ceil((64-x)/2)+ceil((x+1)/2) = 33 stages for every x. LDS 64KB ->
// 2 blocks/CU (occupancy proven non-limiting in round 5).
// ---------------------------------------------------------------------------
__global__ __launch_bounds__(256, 2) void attn_mfma2(
    const unsigned short* __restrict__ Q, const unsigned short* __restrict__ K,
    const unsigned short* __restrict__ Vt, unsigned short* __restrict__ Y)
{
    __shared__ unsigned short Ks[2][16 * 512];  // chunk (sub,kh): 16 keys x 32 d, sub 0..7
    __shared__ unsigned short Vs[2][16 * 512];  // chunk (dt,kq): 16 d x 32 keys, kq 0..3

    const int tid = threadIdx.x;
    const int w = tid >> 6, l = tid & 63;    // 4 waves x 16 q-rows
    const int l15 = l & 15, l4 = l >> 4;

    // XCD-aware remap: XCD r = f%8 handles bh in [3r, 3r+3)
    const int f = (int)blockIdx.y * 32 + (int)blockIdx.x;
    const int r8 = f & 7, j = f >> 3;
    const int bh = r8 * 3 + (j >> 5);
    const int xq = j & 31;

    const size_t base = (size_t)bh * Tn * Dn;   // same size for K ([T][D]) and Vt ([D][T])
    const int b = bh / Hn, h = bh - b * Hn;

    // lane-constant byte offset for PV B-fragment reads (16x16x16 layout)
    const int vlb = (l4 >> 1) * 256 + l15 * 16 + (l4 & 1) * 8;

    // ones B-fragment (bf16 1.0 x4) for the lsum row-sum MFMA
    union { unsigned int u[2]; bf16x4 v; } onesu;
    onesu.u[0] = 0x3F803F80u; onesu.u[1] = 0x3F803F80u;
    const bf16x4 ones = onesu.v;

    for (int half = 0; half < 2; ++half) {
        const int t = half ? xq : (63 - xq);
        const int q0 = t * 64;
        const int qrow = q0 + w * 16 + l15;    // this lane's q (swapped layout)

        bf16x8 aq[2];
#pragma unroll
        for (int kh = 0; kh < 2; ++kh)
            aq[kh] = *reinterpret_cast<const bf16x8*>(
                Q + base + (size_t)qrow * Dn + kh * 32 + l4 * 8);

        f32x4 o[4];
#pragma unroll
        for (int dt = 0; dt < 4; ++dt) o[dt] = (f32x4){0.f, 0.f, 0.f, 0.f};
        f32x4 ol = (f32x4){0.f, 0.f, 0.f, 0.f};   // lsum accumulator (per-row)

        const int nst = (q0 >> 7) + 1;   // 128-key stages this half

        // prologue: all waves done reading LDS (prev half) before overwrite
        __syncthreads();
#pragma unroll
        for (int jj = 0; jj < 4; ++jj) {     // stage tile 0 -> buf 0 (16 chunks / 4 waves)
            const int c = w * 4 + jj;
            const int sub = c >> 1, kh = c & 1;      // K chunk: keys sub*16.., d kh*32..
            async_ld16(K + base + (size_t)(sub * 16 + l15) * Dn + kh * 32 + l4 * 8,
                       &Ks[0][c * 512]);
            const int dt = c >> 2, kq = c & 3;       // V chunk: d dt*16.., keys kq*32..
            async_ld16(Vt + base + (size_t)(dt * 16 + l15) * Tn + kq * 32 + l4 * 8,
                       &Vs[0][c * 512]);
        }

        int cur = 0;
        for (int s = 0; s < nst; ++s) {
            const int k0 = s << 7;
            __syncthreads();   // implicit vmcnt(0): buf[cur] complete; joins waves

            if (s + 1 < nst) {   // prefetch next 128-key tile into buf[cur^1]
                const int kn = k0 + 128;
#pragma unroll
                for (int jj = 0; jj < 4; ++jj) {
                    const int c = w * 4 + jj;
                    const int sub = c >> 1, kh = c & 1;
                    async_ld16(K + base + (size_t)(kn + sub * 16 + l15) * Dn + kh * 32 + l4 * 8,
                               &Ks[cur ^ 1][c * 512]);
                    const int dt = c >> 2, kq = c & 3;
                    async_ld16(Vt + base + (size_t)(dt * 16 + l15) * Tn + kn + kq * 32 + l4 * 8,
                               &Vs[cur ^ 1][c * 512]);
                }
            }

            // S^T = K Q^T: C[col=q(l15)][row=key(l4*4+i)] per key-subtile tt
            f32x4 sfr[8];
            __builtin_amdgcn_s_setprio(1);
#pragma unroll
            for (int tt = 0; tt < 8; ++tt) {
                bf16x8 ak0 = *reinterpret_cast<const bf16x8*>(&Ks[cur][(tt * 2 + 0) * 512 + l * 8]);
                bf16x8 ak1 = *reinterpret_cast<const bf16x8*>(&Ks[cur][(tt * 2 + 1) * 512 + l * 8]);
                f32x4 z = (f32x4){0.f, 0.f, 0.f, 0.f};
                z = __builtin_amdgcn_mfma_f32_16x16x32_bf16(ak0, aq[0], z, 0, 0, 0);
                z = __builtin_amdgcn_mfma_f32_16x16x32_bf16(ak1, aq[1], z, 0, 0, 0);
                sfr[tt] = z;
            }
            __builtin_amdgcn_s_setprio(0);

            // p = exp2(s) (Q pre-scaled); mask covers causal boundary AND the
            // overhang keys past kend on the final stage (key > qrow -> p=0)
            const bool need_mask = (k0 + 127 > q0);
            float p[8][4];
#pragma unroll
            for (int tt = 0; tt < 8; ++tt)
#pragma unroll
                for (int i = 0; i < 4; ++i) {
                    float s2 = sfr[tt][i];
                    if (need_mask && (k0 + tt * 16 + l4 * 4 + i > qrow)) s2 = -1e30f;
                    p[tt][i] = __builtin_amdgcn_exp2f(s2);
                }

            // pack P to bf16 A-fragments (registers only, no LDS)
            bf16x4 pa[8];
#pragma unroll
            for (int tt = 0; tt < 8; ++tt) {
                union { unsigned int u[2]; bf16x4 v; } uu;
                uu.u[0] = cvt_pk_bf16(p[tt][0], p[tt][1]);
                uu.u[1] = cvt_pk_bf16(p[tt][2], p[tt][3]);
                pa[tt] = uu.v;
            }

            // PV: o[dt] += sum_tt mfma_16x16x16(pa[tt], V-frag(dt,tt));
            // lsum:  ol += mfma_16x16x16(pa[tt], ones)  (row-sum of P)
            const char* vb = (const char*)&Vs[cur][0];
            __builtin_amdgcn_s_setprio(1);
#pragma unroll
            for (int tt = 0; tt < 8; ++tt) {
                ol = __builtin_amdgcn_mfma_f32_16x16x16bf16_1k(pa[tt], ones, ol, 0, 0, 0);
#pragma unroll
                for (int dt = 0; dt < 4; ++dt) {
                    bf16x4 bv = *reinterpret_cast<const bf16x4*>(vb + dt * 4096 + tt * 512 + vlb);
                    o[dt] = __builtin_amdgcn_mfma_f32_16x16x16bf16_1k(pa[tt], bv, o[dt], 0, 0, 0);
                }
            }
            __builtin_amdgcn_s_setprio(0);
            cur ^= 1;
        }

        // epilogue: ol[i] is the denominator for output row l4*4+i (no shfl)
#pragma unroll
        for (int i = 0; i < 4; ++i) {
            const float inv = 1.0f / ol[i];
            const int row = q0 + w * 16 + l4 * 4 + i;
#pragma unroll
            for (int dt = 0; dt < 4; ++dt)
                Y[((size_t)(b * Tn + row)) * Cn + h * 64 + dt * 16 + l15] = f2b(o[dt][i] * inv);
        }
    }
}

// ---------------------------------------------------------------------------
// Fallback attention (round-1 verified; Q arrives pre-scaled -> no mul).
// ---------------------------------------------------------------------------
__global__ __launch_bounds__(256, 3) void attn_mfma_fb(
    const unsigned short* __restrict__ Q, const unsigned short* __restrict__ K,
    const unsigned short* __restrict__ V, unsigned short* __restrict__ Y)
{
    __shared__ unsigned short Ks[96 * PAD];
    __shared__ unsigned short Vtl[96 * PAD];
    __shared__ unsigned short Ps[96 * PAD];

    const int tid = threadIdx.x;
    const int w = tid >> 6, l = tid & 63;
    const int l15 = l & 15, l4 = l >> 4;
    const int bh = blockIdx.y;
    const size_t base = (size_t)bh * Tn * Dn;
    const int b = bh / Hn, h = bh - b * Hn;

    for (int half = 0; half < 2; ++half) {
        const int t = half ? (int)blockIdx.x : (63 - (int)blockIdx.x);
        const int q0 = t * 64;

        bf16x8 aq[2];
#pragma unroll
        for (int kh = 0; kh < 2; ++kh)
            aq[kh] = *reinterpret_cast<const bf16x8*>(
                Q + base + (size_t)(q0 + w * 16 + l15) * Dn + kh * 32 + l4 * 8);

        f32x4 o[4];
#pragma unroll
        for (int dt = 0; dt < 4; ++dt) o[dt] = (f32x4){0.f, 0.f, 0.f, 0.f};
        float l_i[4] = {0.f, 0.f, 0.f, 0.f};

        const int kend = q0 + 64;
        for (int k0 = 0; k0 < kend; k0 += 64) {
            __syncthreads();
#pragma unroll
            for (int it = 0; it < 2; ++it) {
                const int s = tid + it * 256;
                const int r = s >> 3, c = (s & 7) * 8;
                *reinterpret_cast<int4*>(&Ks[r * PAD + c]) =
                    *reinterpret_cast<const int4*>(K + base + (size_t)(k0 + r) * Dn + c);
            }
#pragma unroll
            for (int it = 0; it < 2; ++it) {
                const int r = tid & 63, d0 = (tid >> 6) * 8 + it * 32;
                int4 vv = *reinterpret_cast<const int4*>(V + base + (size_t)(k0 + r) * Dn + d0);
                const unsigned short* vu = reinterpret_cast<const unsigned short*>(&vv);
#pragma unroll
                for (int j = 0; j < 8; ++j) Vtl[(d0 + j) * PAD + r] = vu[j];
            }
            __syncthreads();

            f32x4 sfr[4];
#pragma unroll
            for (int tt = 0; tt < 4; ++tt) {
                bf16x8 bk0 = *reinterpret_cast<const bf16x8*>(&Ks[(tt * 16 + l15) * PAD + l4 * 8]);
                bf16x8 bk1 = *reinterpret_cast<const bf16x8*>(&Ks[(tt * 16 + l15) * PAD + 32 + l4 * 8]);
                f32x4 z = (f32x4){0.f, 0.f, 0.f, 0.f};
                z = __builtin_amdgcn_mfma_f32_16x16x32_bf16(aq[0], bk0, z, 0, 0, 0);
                z = __builtin_amdgcn_mfma_f32_16x16x32_bf16(aq[1], bk1, z, 0, 0, 0);
                sfr[tt] = z;
            }

            const bool need_mask = (k0 + 63 > q0);
            float p[4][4];
#pragma unroll
            for (int tt = 0; tt < 4; ++tt) {
                const int cb = k0 + tt * 16 + l15;
                const int rb = q0 + w * 16 + l4 * 4;
#pragma unroll
                for (int i = 0; i < 4; ++i) {
                    float s = sfr[tt][i];
                    if (need_mask && (cb > rb + i)) s = -1e30f;
                    const float e = exp2f(s);
                    p[tt][i] = e;
                    l_i[i] += e;
                }
            }

#pragma unroll
            for (int tt = 0; tt < 4; ++tt)
#pragma unroll
                for (int i = 0; i < 4; ++i)
                    Ps[(w * 16 + l4 * 4 + i) * PAD + tt * 16 + l15] = f2b(p[tt][i]);

            bf16x8 ap0 = *reinterpret_cast<const bf16x8*>(&Ps[(w * 16 + l15) * PAD + l4 * 8]);
            bf16x8 ap1 = *reinterpret_cast<const bf16x8*>(&Ps[(w * 16 + l15) * PAD + 32 + l4 * 8]);
#pragma unroll
            for (int dt = 0; dt < 4; ++dt) {
                bf16x8 bv0 = *reinterpret_cast<const bf16x8*>(&Vtl[(dt * 16 + l15) * PAD + l4 * 8]);
                bf16x8 bv1 = *reinterpret_cast<const bf16x8*>(&Vtl[(dt * 16 + l15) * PAD + 32 + l4 * 8]);
                o[dt] = __builtin_amdgcn_mfma_f32_16x16x32_bf16(ap0, bv0, o[dt], 0, 0, 0);
                o[dt] = __builtin_amdgcn_mfma_f32_16x16x32_bf16(ap1, bv1, o[dt], 0, 0, 0);
            }
        }

#pragma unroll
        for (int i = 0; i < 4; ++i)
#pragma unroll
            for (int off = 1; off < 16; off <<= 1) l_i[i] += __shfl_xor(l_i[i], off);

#pragma unroll
        for (int i = 0; i < 4; ++i) {
            const float inv = 1.0f / l_i[i];
            const int row = q0 + w * 16 + l4 * 4 + i;
#pragma unroll
            for (int dt = 0; dt < 4; ++dt)
                Y[((size_t)(b * Tn + row)) * Cn + h * 64 + dt * 16 + l15] = f2b(o[dt][i] * inv);
        }
    }
}

extern "C" void kernel_launch(void* const* d_in, const int* in_sizes, int n_in,
                              void* d_out, int out_size, void* d_ws, size_t ws_size,
                              hipStream_t stream)
{
    const void* x = d_in[0];
    const void* wqkv = d_in[1];
    const void* wproj = d_in[2];
    const size_t HSZ = (size_t)Bn * Hn * Tn * Dn;   // 6291456 elems
    unsigned short* q = (unsigned short*)d_ws;
    unsigned short* k = q + HSZ;
    unsigned short* v = k + HSZ;          // big path: holds V^T [B,H,D,T]
    unsigned short* R = v + HSZ;          // wqkvT during QKV gemm, y afterwards
    unsigned short* wqkvT = R;            // [2304][768] = 1769472 elems <= HSZ
    unsigned short* y = R;
    unsigned short* wprojT = q;           // fallback: [768][768], reused after attn
    // Big layout adds xb (bf16 copy of x) at 4*HSZ. Need 5*HSZ*2+16 bytes.
    // big2 additionally carves a dedicated wprojT2 slot after the flag.
    const bool big = ws_size >= (size_t)5 * HSZ * 2 + 16;
    unsigned short* xb = R + HSZ;
    int* flag = big ? (int*)(xb + HSZ) : (int*)(R + HSZ);
    unsigned short* wprojT2 = xb + HSZ + 64;   // 128B past flag
    const bool big2 = big &&
        ws_size >= ((size_t)5 * HSZ + 64 + (size_t)Cn * Cn) * 2 + 16;

    if (big) {
        // fused detect + transpose(wqkv) + convert(x) [+ transpose(wproj)]
        prep1_k<<<big2 ? 3648 : 3504, 256, 0, stream>>>(
            wqkv, wqkvT, x, xb, wproj, big2 ? wprojT2 : xb, flag);
        // QKV GEMM writes Q pre-scaled and V directly transposed
        gemm_lds<1><<<dim3(3 * Cn / 128, Mn / 128), 256, 0, stream>>>(
            xb, wqkvT, nullptr, q, k, v, Mn, 3 * Cn, Cn, flag);
        attn_mfma2<<<dim3(Tn / 128, Bn * Hn), 256, 0, stream>>>(q, k, v, y);
        if (big2) {
            gemm_lds<0><<<dim3(Cn / 128, Mn / 128), 256, 0, stream>>>(
                y, wprojT2, d_out, nullptr, nullptr, nullptr, Mn, Cn, Cn, flag);
        } else {
            transpose_w_k<<<dim3(Cn / 64, Cn / 64), 256, 0, stream>>>(wproj, wprojT, Cn, Cn, flag);
            gemm_lds<0><<<dim3(Cn / 128, Mn / 128), 256, 0, stream>>>(
                y, wprojT, d_out, nullptr, nullptr, nullptr, Mn, Cn, Cn, flag);
        }
    } else {
        prep1_k<<<432, 256, 0, stream>>>(wqkv, wqkvT, x, (unsigned short*)d_ws,
                                         wproj, (unsigned short*)d_ws, flag);
        gemm_qkv_fb<<<dim3(3 * Cn / 128, Mn / 128), 256, 0, stream>>>(
            x, wqkvT, q, k, v, Mn, 3 * Cn, Cn, flag);
        attn_mfma_fb<<<dim3(Tn / 128, Bn * Hn), 256, 0, stream>>>(q, k, v, y);
        transpose_w_k<<<dim3(Cn / 64, Cn / 64), 256, 0, stream>>>(wproj, wprojT, Cn, Cn, flag);
        gemm_lds<0><<<dim3(Cn / 128, Mn / 128), 256, 0, stream>>>(
            y, wprojT, d_out, nullptr, nullptr, nullptr, Mn, Cn, Cn, flag);
    }
}

// Round 15
// 277.880 us; speedup vs baseline: 1.2513x; 1.2513x over previous
//
#include <hip/hip_runtime.h>
#include <hip/hip_bf16.h>

#define Bn 2
#define Tn 4096
#define Cn 768
#define Hn 12
#define Dn 64
#define Mn (Bn * Tn)   // 8192
#define PAD 72         // padded LDS row stride (bf16 elems) for attn/transpose
#define QSC 0.18033688011112f   // D^-0.5 * log2(e), folded into Q at gen time

typedef __attribute__((ext_vector_type(8))) short bf16x8;
typedef __attribute__((ext_vector_type(4))) short bf16x4;
typedef __attribute__((ext_vector_type(4))) float f32x4;

typedef const __attribute__((address_space(1))) unsigned int* gas_ptr;
typedef __attribute__((address_space(3))) unsigned int* las_ptr;

__device__ __forceinline__ float b2f(unsigned short u) {
    return __uint_as_float(((unsigned int)u) << 16);
}
__device__ __forceinline__ unsigned short f2b(float f) {
    unsigned int x = __float_as_uint(f);
    x += 0x7FFFu + ((x >> 16) & 1u);   // round-to-nearest-even
    return (unsigned short)(x >> 16);
}
// packed f32x2 -> bf16x2 (single VALU op)
__device__ __forceinline__ unsigned int cvt_pk_bf16(float lo, float hi) {
    unsigned int r;
    asm("v_cvt_pk_bf16_f32 %0, %1, %2" : "=v"(r) : "v"(lo), "v"(hi));
    return r;
}

// Async global->LDS, 16B/lane. LDS dest = wave-uniform base + lane*16.
__device__ __forceinline__ void async_ld16(const unsigned short* g, unsigned short* l) {
    __builtin_amdgcn_global_load_lds((gas_ptr)(const void*)g, (las_ptr)(void*)l, 16, 0, 0);
}

// ---------------------------------------------------------------------------
// prep1: fused {dtype-detect + transpose wqkv + convert x + (opt) transpose
// wproj}. Blocks [0,432): wqkv transpose tiles; [432,3504): x convert;
// [3504,3648): wproj transpose tiles (only when launched with 3648 blocks).
// ---------------------------------------------------------------------------
__global__ __launch_bounds__(256) void prep1_k(
    const void* __restrict__ wqkv, unsigned short* __restrict__ wqkvT,
    const void* __restrict__ x, unsigned short* __restrict__ xb,
    const void* __restrict__ wproj, unsigned short* __restrict__ wprojT,
    int* __restrict__ flag)
{
    __shared__ unsigned short Ts[64][PAD];
    __shared__ int anyf;
    const int tid = threadIdx.x;
    if (tid == 0) anyf = 0;
    __syncthreads();
    {   // per-block detect: 2048 bf16-view samples of wqkv
        int4 v = reinterpret_cast<const int4*>(wqkv)[tid];
        const unsigned short* u = reinterpret_cast<const unsigned short*>(&v);
        int bad = 0;
#pragma unroll
        for (int j = 0; j < 8; ++j) {
            const unsigned int e = (u[j] >> 7) & 0xFFu;
            bad |= (e >= 0x88u) ? 1 : 0;
        }
        if (bad) atomicOr(&anyf, 1);
    }
    __syncthreads();
    const bool f32 = (anyf != 0);
    if (tid == 0 && blockIdx.x == 0) *flag = anyf;

    if (blockIdx.x >= 432 && blockIdx.x < 3504) {
        // convert x -> bf16 flat copy, 8 elems/thread
        const size_t i = ((size_t)(blockIdx.x - 432) * 256 + tid) * 8;
        union { int4 v; unsigned short u[8]; } pk;
        if (f32) {
            const float* p = (const float*)x + i;
            float4 a = *reinterpret_cast<const float4*>(p);
            float4 b = *reinterpret_cast<const float4*>(p + 4);
            float t[8] = {a.x, a.y, a.z, a.w, b.x, b.y, b.z, b.w};
#pragma unroll
            for (int j = 0; j < 8; ++j) pk.u[j] = f2b(t[j]);
        } else {
            pk.v = *reinterpret_cast<const int4*>((const unsigned short*)x + i);
        }
        *reinterpret_cast<int4*>(xb + i) = pk.v;
        return;
    }

    // transpose path: wqkv (blocks < 432) or wproj (blocks >= 3504)
    const bool isW2 = (blockIdx.x >= 3504);
    const void* in = isW2 ? wproj : wqkv;
    unsigned short* out = isW2 ? wprojT : wqkvT;
    const int K = Cn;
    const int N = isW2 ? Cn : 3 * Cn;
    const int id = isW2 ? ((int)blockIdx.x - 3504) : (int)blockIdx.x;
    const int ncols = N / 64;
    const int nB = (id % ncols) * 64, kB = (id / ncols) * 64;
#pragma unroll
    for (int it = 0; it < 2; ++it) {
        const int r = (tid >> 3) + it * 32;   // k-row in tile
        const int c = (tid & 7) * 8;          // n-col chunk
        float t[8];
        if (f32) {
            const float* p = (const float*)in + (size_t)(kB + r) * N + nB + c;
            float4 a = *reinterpret_cast<const float4*>(p);
            float4 b = *reinterpret_cast<const float4*>(p + 4);
            t[0]=a.x;t[1]=a.y;t[2]=a.z;t[3]=a.w;t[4]=b.x;t[5]=b.y;t[6]=b.z;t[7]=b.w;
        } else {
            int4 v = *reinterpret_cast<const int4*>((const unsigned short*)in + (size_t)(kB + r) * N + nB + c);
            const unsigned short* u = reinterpret_cast<const unsigned short*>(&v);
#pragma unroll
            for (int j = 0; j < 8; ++j) t[j] = b2f(u[j]);
        }
#pragma unroll
        for (int j = 0; j < 8; ++j) Ts[c + j][r] = f2b(t[j]);
    }
    __syncthreads();
#pragma unroll
    for (int it = 0; it < 2; ++it) {
        const int n = (tid >> 3) + it * 32;
        const int k = (tid & 7) * 8;
        *reinterpret_cast<int4*>(out + (size_t)(nB + n) * K + kB + k) =
            *reinterpret_cast<const int4*>(&Ts[n][k]);
    }
}

// Transpose weight: in[K][N] (fp32 or bf16 per flag) -> out[N][K] bf16. 64x64 tiles.
// (fallback path only)
__global__ __launch_bounds__(256) void transpose_w_k(
    const void* __restrict__ in, unsigned short* __restrict__ out,
    int K, int N, const int* __restrict__ flag)
{
    __shared__ unsigned short Ts[64][PAD];   // [n][k]
    const int tid = threadIdx.x;
    const int kB = blockIdx.y * 64, nB = blockIdx.x * 64;
    const bool f32 = (*flag != 0);
#pragma unroll
    for (int it = 0; it < 2; ++it) {
        const int r = (tid >> 3) + it * 32;   // k-row in tile
        const int c = (tid & 7) * 8;          // n-col chunk
        float t[8];
        if (f32) {
            const float* p = (const float*)in + (size_t)(kB + r) * N + nB + c;
            float4 a = *reinterpret_cast<const float4*>(p);
            float4 b = *reinterpret_cast<const float4*>(p + 4);
            t[0]=a.x;t[1]=a.y;t[2]=a.z;t[3]=a.w;t[4]=b.x;t[5]=b.y;t[6]=b.z;t[7]=b.w;
        } else {
            int4 v = *reinterpret_cast<const int4*>((const unsigned short*)in + (size_t)(kB + r) * N + nB + c);
            const unsigned short* u = reinterpret_cast<const unsigned short*>(&v);
#pragma unroll
            for (int j = 0; j < 8; ++j) t[j] = b2f(u[j]);
        }
#pragma unroll
        for (int j = 0; j < 8; ++j) Ts[c + j][r] = f2b(t[j]);
    }
    __syncthreads();
#pragma unroll
    for (int it = 0; it < 2; ++it) {
        const int n = (tid >> 3) + it * 32;
        const int k = (tid & 7) * 8;
        *reinterpret_cast<int4*>(out + (size_t)(nB + n) * K + kB + k) =
            *reinterpret_cast<const int4*>(&Ts[n][k]);
    }
}

// ---------------------------------------------------------------------------
// MFMA GEMM v2 (verified round 10/11): 128x128 tile, BK=32, single-barrier
// double-buffered global_load_lds staging, XCD-chunked swizzle.
// EPI==0: row-major store. EPI==1: QKV split, Q pre-scaled by QSC, V
// written transposed [B,H,D,T] (8B packed stores).
// ---------------------------------------------------------------------------
template <int EPI>
__global__ __launch_bounds__(256) void gemm_lds(
    const unsigned short* __restrict__ A, const unsigned short* __restrict__ Bt,
    void* __restrict__ Out, unsigned short* __restrict__ Qo,
    unsigned short* __restrict__ Ko, unsigned short* __restrict__ Vo,
    int M, int N, int K, const int* __restrict__ flag)
{
    __shared__ unsigned short As[2][8 * 512];   // buf x 8 chunks (16 rows x 32 k)
    __shared__ unsigned short Bs[2][8 * 512];
    const int tid = threadIdx.x;
    const int w = tid >> 6, l = tid & 63;
    const int l15 = l & 15, l4 = l >> 4;

    // XCD-chunked swizzle (identity when nwg not divisible by 8)
    const int gx = (int)gridDim.x;
    const int nwg = gx * (int)gridDim.y;
    int fid = (int)blockIdx.y * gx + (int)blockIdx.x;
    if ((nwg & 7) == 0) fid = (fid & 7) * (nwg >> 3) + (fid >> 3);
    const int rowBase = (fid / gx) * 128;
    const int colBase = (fid % gx) * 128;

    const int mq = (w & 1) * 64, nq = (w >> 1) * 64;
    const bool f32 = (*flag != 0);

    f32x4 acc[4][4];
#pragma unroll
    for (int i = 0; i < 4; ++i)
#pragma unroll
        for (int j = 0; j < 4; ++j) acc[i][j] = (f32x4){0.f, 0.f, 0.f, 0.f};

    // stage K-slab 0 -> buf 0: 8 chunks each of A,B; wave w does 2
#pragma unroll
    for (int jj = 0; jj < 2; ++jj) {
        const int c = w * 2 + jj;
        async_ld16(A + (size_t)(rowBase + c * 16 + l15) * K + l4 * 8, &As[0][c * 512]);
        async_ld16(Bt + (size_t)(colBase + c * 16 + l15) * K + l4 * 8, &Bs[0][c * 512]);
    }

    const int nk = K >> 5;
    int cur = 0;
    for (int s = 0; s < nk; ++s) {
        __syncthreads();   // implicit vmcnt(0): buf[cur] landed; joins prior reads of buf[cur^1]

        if (s + 1 < nk) {  // prefetch next slab into buf[cur^1]
            const int kn = (s + 1) << 5;
#pragma unroll
            for (int jj = 0; jj < 2; ++jj) {
                const int c = w * 2 + jj;
                async_ld16(A + (size_t)(rowBase + c * 16 + l15) * K + kn + l4 * 8,
                           &As[cur ^ 1][c * 512]);
                async_ld16(Bt + (size_t)(colBase + c * 16 + l15) * K + kn + l4 * 8,
                           &Bs[cur ^ 1][c * 512]);
            }
        }

        bf16x8 af[4], bf[4];
#pragma unroll
        for (int mt = 0; mt < 4; ++mt)
            af[mt] = *reinterpret_cast<const bf16x8*>(
                &As[cur][((mq >> 4) + mt) * 512 + l * 8]);
#pragma unroll
        for (int nt = 0; nt < 4; ++nt)
            bf[nt] = *reinterpret_cast<const bf16x8*>(
                &Bs[cur][((nq >> 4) + nt) * 512 + l * 8]);
#pragma unroll
        for (int mt = 0; mt < 4; ++mt)
#pragma unroll
            for (int nt = 0; nt < 4; ++nt)
                acc[mt][nt] = __builtin_amdgcn_mfma_f32_16x16x32_bf16(af[mt], bf[nt], acc[mt][nt], 0, 0, 0);
        cur ^= 1;
    }

    // epilogue: C/D layout col=l15, row=l4*4+i
#pragma unroll
    for (int mt = 0; mt < 4; ++mt)
#pragma unroll
        for (int nt = 0; nt < 4; ++nt) {
            const int n0 = colBase + nq + nt * 16 + l15;
            const int m0 = rowBase + mq + mt * 16 + l4 * 4;
            if (EPI == 0) {
#pragma unroll
                for (int i = 0; i < 4; ++i) {
                    if (f32) ((float*)Out)[(size_t)(m0 + i) * N + n0] = acc[mt][nt][i];
                    else ((unsigned short*)Out)[(size_t)(m0 + i) * N + n0] = f2b(acc[mt][nt][i]);
                }
            } else {
                const int sec = n0 / 768;           // uniform over l15 (16-aligned bounds)
                const int cc = n0 - sec * 768;
                const int h = cc >> 6, d = cc & 63;
                const int b = m0 >> 12, t0 = m0 & 4095;   // b uniform over i
                if (sec < 2) {
                    unsigned short* dst = (sec == 0) ? Qo : Ko;
                    const float scl = (sec == 0) ? QSC : 1.0f;   // pre-scale Q
#pragma unroll
                    for (int i = 0; i < 4; ++i)
                        dst[(((size_t)(b * Hn + h) * Tn + t0 + i) * Dn) + d] = f2b(acc[mt][nt][i] * scl);
                } else {
                    // V transposed: vt[b,h,d,t], 4 consecutive t packed into 8B
                    union { unsigned int u[2]; uint2 v; } pk;
                    pk.u[0] = (unsigned int)f2b(acc[mt][nt][0]) |
                              ((unsigned int)f2b(acc[mt][nt][1]) << 16);
                    pk.u[1] = (unsigned int)f2b(acc[mt][nt][2]) |
                              ((unsigned int)f2b(acc[mt][nt][3]) << 16);
                    *reinterpret_cast<uint2*>(
                        &Vo[(((size_t)(b * Hn + h) * Dn + d) * Tn) + t0]) = pk.v;
                }
            }
        }
}

// ---------------------------------------------------------------------------
// Fallback QKV GEMM (verified): VGPR staging with inline fp32->bf16.
// Writes V untransposed; Q pre-scaled by QSC (fallback attn drops its mul).
// ---------------------------------------------------------------------------
__global__ __launch_bounds__(256) void gemm_qkv_fb(
    const void* __restrict__ A, const unsigned short* __restrict__ Bt,
    unsigned short* __restrict__ Qo, unsigned short* __restrict__ Ko,
    unsigned short* __restrict__ Vo, int M, int N, int K,
    const int* __restrict__ flag)
{
    __shared__ unsigned short As[128 * PAD];
    __shared__ unsigned short Bs[128 * PAD];
    const int tid = threadIdx.x;
    const int w = tid >> 6, l = tid & 63;
    const int l15 = l & 15, l4 = l >> 4;
    const int rowBase = blockIdx.y * 128;
    const int colBase = blockIdx.x * 128;
    const int mq = (w & 1) * 64, nq = (w >> 1) * 64;
    const bool af32 = (*flag != 0);

    f32x4 acc[4][4];
#pragma unroll
    for (int i = 0; i < 4; ++i)
#pragma unroll
        for (int j = 0; j < 4; ++j) acc[i][j] = (f32x4){0.f, 0.f, 0.f, 0.f};

    for (int k0 = 0; k0 < K; k0 += 64) {
        __syncthreads();
#pragma unroll
        for (int it = 0; it < 4; ++it) {
            const int s = tid + it * 256;
            const int r = s >> 3, c = (s & 7) * 8;
            union { int4 v; unsigned short u[8]; } pk;
            if (af32) {
                const float* p = (const float*)A + (size_t)(rowBase + r) * K + k0 + c;
                float4 a = *reinterpret_cast<const float4*>(p);
                float4 b = *reinterpret_cast<const float4*>(p + 4);
                float t[8] = {a.x, a.y, a.z, a.w, b.x, b.y, b.z, b.w};
#pragma unroll
                for (int j = 0; j < 8; ++j) pk.u[j] = f2b(t[j]);
            } else {
                pk.v = *reinterpret_cast<const int4*>(
                    (const unsigned short*)A + (size_t)(rowBase + r) * K + k0 + c);
            }
            *reinterpret_cast<int4*>(&As[r * PAD + c]) = pk.v;
            *reinterpret_cast<int4*>(&Bs[r * PAD + c]) =
                *reinterpret_cast<const int4*>(Bt + (size_t)(colBase + r) * K + k0 + c);
        }
        __syncthreads();
#pragma unroll
        for (int kk = 0; kk < 64; kk += 32) {
            bf16x8 af[4], bf[4];
#pragma unroll
            for (int mt = 0; mt < 4; ++mt)
                af[mt] = *reinterpret_cast<const bf16x8*>(&As[(mq + mt * 16 + l15) * PAD + kk + l4 * 8]);
#pragma unroll
            for (int nt = 0; nt < 4; ++nt)
                bf[nt] = *reinterpret_cast<const bf16x8*>(&Bs[(nq + nt * 16 + l15) * PAD + kk + l4 * 8]);
#pragma unroll
            for (int mt = 0; mt < 4; ++mt)
#pragma unroll
                for (int nt = 0; nt < 4; ++nt)
                    acc[mt][nt] = __builtin_amdgcn_mfma_f32_16x16x32_bf16(af[mt], bf[nt], acc[mt][nt], 0, 0, 0);
        }
    }

#pragma unroll
    for (int mt = 0; mt < 4; ++mt)
#pragma unroll
        for (int i = 0; i < 4; ++i) {
            const int m = rowBase + mq + mt * 16 + l4 * 4 + i;
#pragma unroll
            for (int nt = 0; nt < 4; ++nt) {
                const int n0 = colBase + nq + nt * 16 + l15;
                const int sec = n0 / 768;
                const int cc = n0 - sec * 768;
                const int h = cc >> 6, d = cc & 63;
                const int b = m >> 12, t = m & 4095;
                unsigned short* dst = (sec == 0) ? Qo : (sec == 1) ? Ko : Vo;
                const float scl = (sec == 0) ? QSC : 1.0f;
                dst[(((size_t)(b * Hn + h) * Tn + t) * Dn) + d] = f2b(acc[mt][nt][i] * scl);
            }
        }
}

// ---------------------------------------------------------------------------
// MFMA flash attention (VERIFIED round 13, reverted from the round-14
// KVBLK=128 regression: 64KB LDS -> 2 blocks/CU fell below the latency-
// hiding knee, attn 122->188us). This 64-key / 32KB / >=3 blocks/CU
// structure is the measured floor: folded-pair balanced blocks, XCD-aware
// bh grouping, double-buffered global_load_lds staging in fragment-chunk
// order, swapped QK^T, register-direct PV via mfma_16x16x16bf16_1k,
// Q pre-scaled (no softmax mul), lsum via MFMA row-sum (no shuffles),
// s_setprio around MFMA clusters, __builtin_amdgcn_exp2f.
// ---------------------------------------------------------------------------
__global__ __launch_bounds__(256, 5) void attn_mfma2(
    const unsigned short* __restrict__ Q, const unsigned short* __restrict__ K,
    const unsigned short* __restrict__ Vt, unsigned short* __restrict__ Y)
{
    __shared__ unsigned short Ks[2][8 * 512];   // chunk (tt,kh): 16 keys x 32 d
    __shared__ unsigned short Vs[2][8 * 512];   // chunk (dt,kh): 16 d x 32 keys

    const int tid = threadIdx.x;
    const int w = tid >> 6, l = tid & 63;    // 4 waves x 16 q-rows
    const int l15 = l & 15, l4 = l >> 4;

    // XCD-aware remap: XCD r = f%8 handles bh in [3r, 3r+3)
    const int f = (int)blockIdx.y * 32 + (int)blockIdx.x;
    const int r8 = f & 7, j = f >> 3;
    const int bh = r8 * 3 + (j >> 5);
    const int xq = j & 31;

    const size_t base = (size_t)bh * Tn * Dn;   // same size for K ([T][D]) and Vt ([D][T])
    const int b = bh / Hn, h = bh - b * Hn;

    // lane-constant byte offset for PV B-fragment reads (16x16x16 layout)
    const int vlb = (l4 >> 1) * 256 + l15 * 16 + (l4 & 1) * 8;

    // ones B-fragment (bf16 1.0 x4) for the lsum row-sum MFMA
    union { unsigned int u[2]; bf16x4 v; } onesu;
    onesu.u[0] = 0x3F803F80u; onesu.u[1] = 0x3F803F80u;
    const bf16x4 ones = onesu.v;

    for (int half = 0; half < 2; ++half) {
        const int t = half ? xq : (63 - xq);
        const int q0 = t * 64;
        const int qrow = q0 + w * 16 + l15;    // this lane's q (swapped layout)

        bf16x8 aq[2];
#pragma unroll
        for (int kh = 0; kh < 2; ++kh)
            aq[kh] = *reinterpret_cast<const bf16x8*>(
                Q + base + (size_t)qrow * Dn + kh * 32 + l4 * 8);

        f32x4 o[4];
#pragma unroll
        for (int dt = 0; dt < 4; ++dt) o[dt] = (f32x4){0.f, 0.f, 0.f, 0.f};
        f32x4 ol = (f32x4){0.f, 0.f, 0.f, 0.f};   // lsum accumulator (per-row)

        const int nst = (q0 >> 6) + 1;   // 64-key stages this half

        // prologue: all waves done reading LDS (prev half) before overwrite
        __syncthreads();
#pragma unroll
        for (int jj = 0; jj < 2; ++jj) {     // stage tile 0 -> buf 0
            const int c = w * 2 + jj;
            const int sub = c >> 1, kh = c & 1;
            async_ld16(K + base + (size_t)(sub * 16 + l15) * Dn + kh * 32 + l4 * 8,
                       &Ks[0][c * 512]);
            async_ld16(Vt + base + (size_t)(sub * 16 + l15) * Tn + kh * 32 + l4 * 8,
                       &Vs[0][c * 512]);
        }

        int cur = 0;
        for (int s = 0; s < nst; ++s) {
            const int k0 = s << 6;
            __syncthreads();   // implicit vmcnt(0): buf[cur] complete; joins waves

            if (s + 1 < nst) {   // prefetch next tile into buf[cur^1]
                const int kn = k0 + 64;
#pragma unroll
                for (int jj = 0; jj < 2; ++jj) {
                    const int c = w * 2 + jj;
                    const int sub = c >> 1, kh = c & 1;
                    async_ld16(K + base + (size_t)(kn + sub * 16 + l15) * Dn + kh * 32 + l4 * 8,
                               &Ks[cur ^ 1][c * 512]);
                    async_ld16(Vt + base + (size_t)(sub * 16 + l15) * Tn + kn + kh * 32 + l4 * 8,
                               &Vs[cur ^ 1][c * 512]);
                }
            }

            // S^T = K Q^T: C[col=q(l15)][row=key(l4*4+i)] per key-subtile tt
            f32x4 sfr[4];
            __builtin_amdgcn_s_setprio(1);
#pragma unroll
            for (int tt = 0; tt < 4; ++tt) {
                bf16x8 ak0 = *reinterpret_cast<const bf16x8*>(&Ks[cur][(tt * 2 + 0) * 512 + l * 8]);
                bf16x8 ak1 = *reinterpret_cast<const bf16x8*>(&Ks[cur][(tt * 2 + 1) * 512 + l * 8]);
                f32x4 z = (f32x4){0.f, 0.f, 0.f, 0.f};
                z = __builtin_amdgcn_mfma_f32_16x16x32_bf16(ak0, aq[0], z, 0, 0, 0);
                z = __builtin_amdgcn_mfma_f32_16x16x32_bf16(ak1, aq[1], z, 0, 0, 0);
                sfr[tt] = z;
            }
            __builtin_amdgcn_s_setprio(0);

            // p = exp2(s) (Q pre-scaled), causal mask only on the last stage
            const bool need_mask = (k0 + 63 > q0);
            float p[4][4];
#pragma unroll
            for (int tt = 0; tt < 4; ++tt)
#pragma unroll
                for (int i = 0; i < 4; ++i) {
                    float s2 = sfr[tt][i];
                    if (need_mask && (k0 + tt * 16 + l4 * 4 + i > qrow)) s2 = -1e30f;
                    p[tt][i] = __builtin_amdgcn_exp2f(s2);
                }

            // pack P to bf16 A-fragments (registers only, no LDS)
            bf16x4 pa[4];
#pragma unroll
            for (int tt = 0; tt < 4; ++tt) {
                union { unsigned int u[2]; bf16x4 v; } uu;
                uu.u[0] = cvt_pk_bf16(p[tt][0], p[tt][1]);
                uu.u[1] = cvt_pk_bf16(p[tt][2], p[tt][3]);
                pa[tt] = uu.v;
            }

            // PV: o[dt] += sum_tt mfma_16x16x16(pa[tt], V-frag(dt,tt));
            // lsum:  ol += mfma_16x16x16(pa[tt], ones)  (row-sum of P)
            const char* vb = (const char*)&Vs[cur][0];
            __builtin_amdgcn_s_setprio(1);
#pragma unroll
            for (int tt = 0; tt < 4; ++tt) {
                ol = __builtin_amdgcn_mfma_f32_16x16x16bf16_1k(pa[tt], ones, ol, 0, 0, 0);
#pragma unroll
                for (int dt = 0; dt < 4; ++dt) {
                    bf16x4 bv = *reinterpret_cast<const bf16x4*>(vb + dt * 2048 + tt * 512 + vlb);
                    o[dt] = __builtin_amdgcn_mfma_f32_16x16x16bf16_1k(pa[tt], bv, o[dt], 0, 0, 0);
                }
            }
            __builtin_amdgcn_s_setprio(0);
            cur ^= 1;
        }

        // epilogue: ol[i] is the denominator for output row l4*4+i (no shfl)
#pragma unroll
        for (int i = 0; i < 4; ++i) {
            const float inv = 1.0f / ol[i];
            const int row = q0 + w * 16 + l4 * 4 + i;
#pragma unroll
            for (int dt = 0; dt < 4; ++dt)
                Y[((size_t)(b * Tn + row)) * Cn + h * 64 + dt * 16 + l15] = f2b(o[dt][i] * inv);
        }
    }
}

// ---------------------------------------------------------------------------
// Fallback attention (round-1 verified; Q arrives pre-scaled -> no mul).
// ---------------------------------------------------------------------------
__global__ __launch_bounds__(256, 3) void attn_mfma_fb(
    const unsigned short* __restrict__ Q, const unsigned short* __restrict__ K,
    const unsigned short* __restrict__ V, unsigned short* __restrict__ Y)
{
    __shared__ unsigned short Ks[96 * PAD];
    __shared__ unsigned short Vtl[96 * PAD];
    __shared__ unsigned short Ps[96 * PAD];

    const int tid = threadIdx.x;
    const int w = tid >> 6, l = tid & 63;
    const int l15 = l & 15, l4 = l >> 4;
    const int bh = blockIdx.y;
    const size_t base = (size_t)bh * Tn * Dn;
    const int b = bh / Hn, h = bh - b * Hn;

    for (int half = 0; half < 2; ++half) {
        const int t = half ? (int)blockIdx.x : (63 - (int)blockIdx.x);
        const int q0 = t * 64;

        bf16x8 aq[2];
#pragma unroll
        for (int kh = 0; kh < 2; ++kh)
            aq[kh] = *reinterpret_cast<const bf16x8*>(
                Q + base + (size_t)(q0 + w * 16 + l15) * Dn + kh * 32 + l4 * 8);

        f32x4 o[4];
#pragma unroll
        for (int dt = 0; dt < 4; ++dt) o[dt] = (f32x4){0.f, 0.f, 0.f, 0.f};
        float l_i[4] = {0.f, 0.f, 0.f, 0.f};

        const int kend = q0 + 64;
        for (int k0 = 0; k0 < kend; k0 += 64) {
            __syncthreads();
#pragma unroll
            for (int it = 0; it < 2; ++it) {
                const int s = tid + it * 256;
                const int r = s >> 3, c = (s & 7) * 8;
                *reinterpret_cast<int4*>(&Ks[r * PAD + c]) =
                    *reinterpret_cast<const int4*>(K + base + (size_t)(k0 + r) * Dn + c);
            }
#pragma unroll
            for (int it = 0; it < 2; ++it) {
                const int r = tid & 63, d0 = (tid >> 6) * 8 + it * 32;
                int4 vv = *reinterpret_cast<const int4*>(V + base + (size_t)(k0 + r) * Dn + d0);
                const unsigned short* vu = reinterpret_cast<const unsigned short*>(&vv);
#pragma unroll
                for (int j = 0; j < 8; ++j) Vtl[(d0 + j) * PAD + r] = vu[j];
            }
            __syncthreads();

            f32x4 sfr[4];
#pragma unroll
            for (int tt = 0; tt < 4; ++tt) {
                bf16x8 bk0 = *reinterpret_cast<const bf16x8*>(&Ks[(tt * 16 + l15) * PAD + l4 * 8]);
                bf16x8 bk1 = *reinterpret_cast<const bf16x8*>(&Ks[(tt * 16 + l15) * PAD + 32 + l4 * 8]);
                f32x4 z = (f32x4){0.f, 0.f, 0.f, 0.f};
                z = __builtin_amdgcn_mfma_f32_16x16x32_bf16(aq[0], bk0, z, 0, 0, 0);
                z = __builtin_amdgcn_mfma_f32_16x16x32_bf16(aq[1], bk1, z, 0, 0, 0);
                sfr[tt] = z;
            }

            const bool need_mask = (k0 + 63 > q0);
            float p[4][4];
#pragma unroll
            for (int tt = 0; tt < 4; ++tt) {
                const int cb = k0 + tt * 16 + l15;
                const int rb = q0 + w * 16 + l4 * 4;
#pragma unroll
                for (int i = 0; i < 4; ++i) {
                    float s = sfr[tt][i];
                    if (need_mask && (cb > rb + i)) s = -1e30f;
                    const float e = exp2f(s);
                    p[tt][i] = e;
                    l_i[i] += e;
                }
            }

#pragma unroll
            for (int tt = 0; tt < 4; ++tt)
#pragma unroll
                for (int i = 0; i < 4; ++i)
                    Ps[(w * 16 + l4 * 4 + i) * PAD + tt * 16 + l15] = f2b(p[tt][i]);

            bf16x8 ap0 = *reinterpret_cast<const bf16x8*>(&Ps[(w * 16 + l15) * PAD + l4 * 8]);
            bf16x8 ap1 = *reinterpret_cast<const bf16x8*>(&Ps[(w * 16 + l15) * PAD + 32 + l4 * 8]);
#pragma unroll
            for (int dt = 0; dt < 4; ++dt) {
                bf16x8 bv0 = *reinterpret_cast<const bf16x8*>(&Vtl[(dt * 16 + l15) * PAD + l4 * 8]);
                bf16x8 bv1 = *reinterpret_cast<const bf16x8*>(&Vtl[(dt * 16 + l15) * PAD + 32 + l4 * 8]);
                o[dt] = __builtin_amdgcn_mfma_f32_16x16x32_bf16(ap0, bv0, o[dt], 0, 0, 0);
                o[dt] = __builtin_amdgcn_mfma_f32_16x16x32_bf16(ap1, bv1, o[dt], 0, 0, 0);
            }
        }

#pragma unroll
        for (int i = 0; i < 4; ++i)
#pragma unroll
            for (int off = 1; off < 16; off <<= 1) l_i[i] += __shfl_xor(l_i[i], off);

#pragma unroll
        for (int i = 0; i < 4; ++i) {
            const float inv = 1.0f / l_i[i];
            const int row = q0 + w * 16 + l4 * 4 + i;
#pragma unroll
            for (int dt = 0; dt < 4; ++dt)
                Y[((size_t)(b * Tn + row)) * Cn + h * 64 + dt * 16 + l15] = f2b(o[dt][i] * inv);
        }
    }
}

extern "C" void kernel_launch(void* const* d_in, const int* in_sizes, int n_in,
                              void* d_out, int out_size, void* d_ws, size_t ws_size,
                              hipStream_t stream)
{
    const void* x = d_in[0];
    const void* wqkv = d_in[1];
    const void* wproj = d_in[2];
    const size_t HSZ = (size_t)Bn * Hn * Tn * Dn;   // 6291456 elems
    unsigned short* q = (unsigned short*)d_ws;
    unsigned short* k = q + HSZ;
    unsigned short* v = k + HSZ;          // big path: holds V^T [B,H,D,T]
    unsigned short* R = v + HSZ;          // wqkvT during QKV gemm, y afterwards
    unsigned short* wqkvT = R;            // [2304][768] = 1769472 elems <= HSZ
    unsigned short* y = R;
    unsigned short* wprojT = q;           // fallback: [768][768], reused after attn
    // Big layout adds xb (bf16 copy of x) at 4*HSZ. Need 5*HSZ*2+16 bytes.
    // big2 additionally carves a dedicated wprojT2 slot after the flag.
    const bool big = ws_size >= (size_t)5 * HSZ * 2 + 16;
    unsigned short* xb = R + HSZ;
    int* flag = big ? (int*)(xb + HSZ) : (int*)(R + HSZ);
    unsigned short* wprojT2 = xb + HSZ + 64;   // 128B past flag
    const bool big2 = big &&
        ws_size >= ((size_t)5 * HSZ + 64 + (size_t)Cn * Cn) * 2 + 16;

    if (big) {
        // fused detect + transpose(wqkv) + convert(x) [+ transpose(wproj)]
        prep1_k<<<big2 ? 3648 : 3504, 256, 0, stream>>>(
            wqkv, wqkvT, x, xb, wproj, big2 ? wprojT2 : xb, flag);
        // QKV GEMM writes Q pre-scaled and V directly transposed
        gemm_lds<1><<<dim3(3 * Cn / 128, Mn / 128), 256, 0, stream>>>(
            xb, wqkvT, nullptr, q, k, v, Mn, 3 * Cn, Cn, flag);
        attn_mfma2<<<dim3(Tn / 128, Bn * Hn), 256, 0, stream>>>(q, k, v, y);
        if (big2) {
            gemm_lds<0><<<dim3(Cn / 128, Mn / 128), 256, 0, stream>>>(
                y, wprojT2, d_out, nullptr, nullptr, nullptr, Mn, Cn, Cn, flag);
        } else {
            transpose_w_k<<<dim3(Cn / 64, Cn / 64), 256, 0, stream>>>(wproj, wprojT, Cn, Cn, flag);
            gemm_lds<0><<<dim3(Cn / 128, Mn / 128), 256, 0, stream>>>(
                y, wprojT, d_out, nullptr, nullptr, nullptr, Mn, Cn, Cn, flag);
        }
    } else {
        prep1_k<<<432, 256, 0, stream>>>(wqkv, wqkvT, x, (unsigned short*)d_ws,
                                         wproj, (unsigned short*)d_ws, flag);
        gemm_qkv_fb<<<dim3(3 * Cn / 128, Mn / 128), 256, 0, stream>>>(
            x, wqkvT, q, k, v, Mn, 3 * Cn, Cn, flag);
        attn_mfma_fb<<<dim3(Tn / 128, Bn * Hn), 256, 0, stream>>>(q, k, v, y);
        transpose_w_k<<<dim3(Cn / 64, Cn / 64), 256, 0, stream>>>(wproj, wprojT, Cn, Cn, flag);
        gemm_lds<0><<<dim3(Cn / 128, Mn / 128), 256, 0, stream>>>(
            y, wprojT, d_out, nullptr, nullptr, nullptr, Mn, Cn, Cn, flag);
    }
}